// Round 11
// baseline (87.316 us; speedup 1.0000x reference)
//
#include <hip/hip_runtime.h>

// RegionSelection: bilinear 2x upsample of attention map (8,1,80,80)->(8,1,160,160),
// per-batch rank-1921 threshold (k=int(0.3*6400)=1920, threshold=topv[:,k]),
// mask = up >= thr, weighted = local_feat*(mask+0.1).
// Outputs concatenated: weighted (8*256*160*160 fp32) then mask (8*160*160 fp32).
// d_ws: bit-packed mask, 400 ull per batch (1 bit per upsampled element).

#define NIN   6400    // 80*80
#define NUP   25600   // 160*160
#define KRANK 1921u   // (k+1)-th largest == topv[:, k]

typedef float f32x4 __attribute__((ext_vector_type(4)));

// Wave-parallel "find bin containing rank `rem_in` counting from the top" over
// NBINS bins. Two-level: 64 chunk sums + shfl suffix-scan, then a parallel
// scan of the selected chunk. Executed by wave 0; result -> s_bcast.
template <int NBINS>
__device__ inline void find_bin(const unsigned* s_hist, unsigned rem_in,
                                unsigned* s_bcast, int tid)
{
    constexpr int CHUNK = NBINS / 64;
    if (tid < 64) {
        const int lane = tid;
        unsigned csum = 0;
        #pragma unroll
        for (int k = 0; k < CHUNK; ++k) csum += s_hist[lane * CHUNK + k];
        unsigned suff = csum;
        #pragma unroll
        for (int off = 1; off < 64; off <<= 1) {
            unsigned o = __shfl_down(suff, off);
            if (lane + off < 64) suff += o;
        }
        unsigned suff_next = __shfl_down(suff, 1);
        if (lane == 63) suff_next = 0;
        const bool hit = (suff >= rem_in) & (suff_next < rem_in);
        unsigned long long bmask = __ballot(hit);
        const int src = (int)__builtin_ctzll(bmask);
        const unsigned r_chunk = __shfl(rem_in - suff_next, src);
        const int      cbase   = src * CHUNK;
        unsigned h = (lane < CHUNK) ? s_hist[cbase + lane] : 0u;
        unsigned ssum = h;
        #pragma unroll
        for (int off = 1; off < CHUNK; off <<= 1) {
            unsigned o = __shfl_down(ssum, off);
            if (lane + off < CHUNK) ssum += o;
        }
        unsigned ssum_next = __shfl_down(ssum, 1);
        if (lane >= CHUNK - 1) ssum_next = 0;
        const bool hit2 = (lane < CHUNK) & (ssum >= r_chunk) & (ssum_next < r_chunk);
        if (hit2) {
            s_bcast[0] = (unsigned)(cbase + lane);
            s_bcast[1] = r_chunk - ssum_next;
        }
    }
}

// Same, over the SUM of two 4096-bin sub-histograms (wave-parity split).
__device__ inline void find_bin_4096x2(const unsigned* h0, const unsigned* h1,
                                       unsigned rem_in, unsigned* s_bcast, int tid)
{
    if (tid < 64) {
        const int lane = tid;
        unsigned csum = 0;
        #pragma unroll
        for (int k = 0; k < 64; ++k) {
            const int idx = lane * 64 + k;
            csum += h0[idx] + h1[idx];
        }
        unsigned suff = csum;
        #pragma unroll
        for (int off = 1; off < 64; off <<= 1) {
            unsigned o = __shfl_down(suff, off);
            if (lane + off < 64) suff += o;
        }
        unsigned suff_next = __shfl_down(suff, 1);
        if (lane == 63) suff_next = 0;
        const bool hit = (suff >= rem_in) & (suff_next < rem_in);
        unsigned long long bmask = __ballot(hit);
        const int src = (int)__builtin_ctzll(bmask);
        const unsigned r_chunk = __shfl(rem_in - suff_next, src);
        const int      cbase   = src * 64;
        unsigned hsum = h0[cbase + lane] + h1[cbase + lane];
        unsigned ssum = hsum;
        #pragma unroll
        for (int off = 1; off < 64; off <<= 1) {
            unsigned o = __shfl_down(ssum, off);
            if (lane + off < 64) ssum += o;
        }
        unsigned ssum_next = __shfl_down(ssum, 1);
        if (lane == 63) ssum_next = 0;
        const bool hit2 = (ssum >= r_chunk) & (ssum_next < r_chunk);
        if (hit2) {
            s_bcast[0] = (unsigned)(cbase + lane);
            s_bcast[1] = r_chunk - ssum_next;
        }
    }
}

__global__ __launch_bounds__(1024) void upsample_select_kernel(
    const float* __restrict__ att, float* __restrict__ mask_out,
    unsigned long long* __restrict__ ws_bits)
{
    __shared__ float    s_in[NIN + 81];  // +81: zero pad so y1/x1 overruns are safe
    __shared__ unsigned s_hist[8192];    // 2 x 4096 sub-histograms (pass 1)
    __shared__ unsigned s_bcast[2];

    const int b   = blockIdx.x;
    const int tid = threadIdx.x;

    const float* in = att + b * NIN;
    for (int i = tid; i < NIN; i += 1024) s_in[i] = in[i];
    if (tid < 81) s_in[NIN + tid] = 0.0f;
    __syncthreads();

    // Branch-free bilinear 2x upsample, half-pixel centers. Edge clamping via
    // fmaxf (low edge) and wy/wx := 0 at the high edge; out-of-row/pad reads
    // are multiplied by exactly 0.0f -> results bit-identical to the
    // branchy version validated in rounds 1-9 (absmax==0).
    unsigned ub[25];
    #pragma unroll
    for (int j = 0; j < 25; ++j) {
        int i = j * 1024 + tid;
        int r = i / 160;
        int c = i - r * 160;
        float yf = fmaxf(0.5f * (float)r - 0.25f, 0.0f);
        int   y0 = (int)yf;
        float wy = yf - (float)y0;
        wy = (y0 >= 79) ? 0.0f : wy;
        float xf = fmaxf(0.5f * (float)c - 0.25f, 0.0f);
        int   x0 = (int)xf;
        float wx = xf - (float)x0;
        wx = (x0 >= 79) ? 0.0f : wx;
        const float* p0 = &s_in[y0 * 80 + x0];
        float a00 = p0[0], a01 = p0[1];        // merge -> ds_read2_b32
        float a10 = p0[80], a11 = p0[81];
        float top = a00 * (1.0f - wx) + a01 * wx;
        float bot = a10 * (1.0f - wx) + a11 * wx;
        float v   = top * (1.0f - wy) + bot * wy;
        ub[j] = __float_as_uint(v);   // v in [0,1) -> uint order == float order
    }

    // ---- exact radix select, 3 passes: bits [30:19], [18:9], [8:0] ----
    unsigned* myh = s_hist + ((tid >> 6) & 1) * 4096;
    for (int i = tid; i < 8192; i += 1024) s_hist[i] = 0;
    __syncthreads();
    #pragma unroll
    for (int j = 0; j < 25; ++j) atomicAdd(&myh[ub[j] >> 19], 1u);  // < 4096
    __syncthreads();
    find_bin_4096x2(s_hist, s_hist + 4096, KRANK, s_bcast, tid);
    __syncthreads();
    const unsigned p1  = s_bcast[0];
    unsigned       rem = s_bcast[1];
    __syncthreads();

    for (int i = tid; i < 1024; i += 1024) s_hist[i] = 0;
    __syncthreads();
    #pragma unroll
    for (int j = 0; j < 25; ++j) {
        unsigned u = ub[j];
        if ((u >> 19) == p1) atomicAdd(&s_hist[(u >> 9) & 1023u], 1u);
    }
    __syncthreads();
    find_bin<1024>(s_hist, rem, s_bcast, tid);
    __syncthreads();
    const unsigned pref2 = (p1 << 10) | s_bcast[0];    // bits [30:9]
    rem = s_bcast[1];
    __syncthreads();

    for (int i = tid; i < 512; i += 1024) s_hist[i] = 0;
    __syncthreads();
    #pragma unroll
    for (int j = 0; j < 25; ++j) {
        unsigned u = ub[j];
        if ((u >> 9) == pref2) atomicAdd(&s_hist[u & 511u], 1u);
    }
    __syncthreads();
    find_bin<512>(s_hist, rem, s_bcast, tid);
    __syncthreads();
    const unsigned thr_bits = (pref2 << 9) | s_bcast[0];

    // mask outputs: fp32 plane (required output) + bit-packed plane (for the
    // streaming kernel). Same values, same >= comparison -> identical set.
    float*              mptr  = mask_out + b * NUP;
    unsigned long long* wbptr = ws_bits + b * 400;   // 400 ull = 25600 bits
    const int lane = tid & 63;
    const int wv   = tid >> 6;
    #pragma unroll
    for (int j = 0; j < 25; ++j) {
        const bool sel = (ub[j] >= thr_bits);
        mptr[j * 1024 + tid] = sel ? 1.0f : 0.0f;
        unsigned long long bal = __ballot(sel);     // bit i = element j*1024+wv*64+i
        if (lane == 0) wbptr[j * 16 + wv] = bal;
    }
}

// weighted = local_feat * (mask + 0.1).
// One block per (b,c) plane; bit-packed mask in LDS (3.2 KB).
// ESTABLISHED: nt LOAD + PLAIN store (r6/r7/r8 A/B), full unroll for 25-deep
// MLP (r10, -10us). THIS ROUND: issue all 25 nt feat-loads BEFORE the s_bits
// staging + barrier, so the mask L2 round-trip and __syncthreads execute
// while the feat loads are in flight (removes per-block dead time at
// stream start).
__global__ __launch_bounds__(256) void apply_mask_kernel(
    const f32x4* __restrict__ feat, const unsigned* __restrict__ bits,
    f32x4* __restrict__ out)
{
    __shared__ unsigned s_bits[800];

    const int tid   = threadIdx.x;
    const int plane = blockIdx.x;          // b*256 + c
    const int b     = plane >> 8;

    const f32x4* fp = feat + plane * 6400 + tid;
    f32x4*       op = out  + plane * 6400 + tid;

    // 1) issue the full feat read stream first (25 outstanding nt loads)
    f32x4 v[25];
    #pragma unroll
    for (int i = 0; i < 25; ++i)
        v[i] = __builtin_nontemporal_load(fp + i * 256);

    // 2) stage mask bits + barrier -- hidden under the loads above
    const unsigned* gb = bits + b * 800;
    #pragma unroll
    for (int k = 0; k < 3; ++k) s_bits[tid + k * 256] = gb[tid + k * 256];
    if (tid < 32) s_bits[768 + tid] = gb[768 + tid];
    __syncthreads();

    // 3) weight + store as each load retires (in issue order)
    #pragma unroll
    for (int i = 0; i < 25; ++i) {
        const unsigned u   = (unsigned)(i * 256 + tid);        // f32x4 index in plane
        const unsigned nib = s_bits[u >> 3] >> ((u & 7u) * 4u);
        f32x4 w;
        w.x = (nib & 1u) ? 1.1f : 0.1f;   // 1.0f+0.1f == 1.1f bitwise (0x3F8CCCCD)
        w.y = (nib & 2u) ? 1.1f : 0.1f;
        w.z = (nib & 4u) ? 1.1f : 0.1f;
        w.w = (nib & 8u) ? 1.1f : 0.1f;
        op[i * 256] = v[i] * w;           // plain store
    }
}

extern "C" void kernel_launch(void* const* d_in, const int* in_sizes, int n_in,
                              void* d_out, int out_size, void* d_ws, size_t ws_size,
                              hipStream_t stream)
{
    const float* local_feat = (const float*)d_in[0];   // (8,256,160,160) fp32
    const float* att        = (const float*)d_in[1];   // (8,1,80,80) fp32
    // d_in[2] = spatial_scale (==2, fixed by problem shapes)

    float* out      = (float*)d_out;
    float* mask_out = out + 8 * 256 * 160 * 160;       // second output region

    upsample_select_kernel<<<8, 1024, 0, stream>>>(
        att, mask_out, (unsigned long long*)d_ws);

    apply_mask_kernel<<<2048, 256, 0, stream>>>(
        (const f32x4*)local_feat, (const unsigned*)d_ws, (f32x4*)out);
}

// Round 12
// 86.257 us; speedup vs baseline: 1.0123x; 1.0123x over previous
//
#include <hip/hip_runtime.h>

// RegionSelection: bilinear 2x upsample of attention map (8,1,80,80)->(8,1,160,160),
// per-batch rank-1921 threshold (k=int(0.3*6400)=1920, threshold=topv[:,k]),
// mask = up >= thr, weighted = local_feat*(mask+0.1).
// Outputs concatenated: weighted (8*256*160*160 fp32) then mask (8*160*160 fp32).
// d_ws: bit-packed mask, 400 ull per batch. Select writes ONLY the bitmask;
// the fp32 mask plane is materialized by the apply kernel (c<8 blocks) from
// the same bits -> identical values, but the 800KB write is spread over 64
// CUs and hidden under the 420MB stream instead of draining from 8 CUs.

#define NIN   6400    // 80*80
#define NUP   25600   // 160*160
#define KRANK 1921u   // (k+1)-th largest == topv[:, k]

typedef float f32x4 __attribute__((ext_vector_type(4)));

// Wave-parallel "find bin containing rank `rem_in` counting from the top" over
// NBINS bins. Two-level: 64 chunk sums + shfl suffix-scan, then a parallel
// scan of the selected chunk. Executed by wave 0; result -> s_bcast.
template <int NBINS>
__device__ inline void find_bin(const unsigned* s_hist, unsigned rem_in,
                                unsigned* s_bcast, int tid)
{
    constexpr int CHUNK = NBINS / 64;
    if (tid < 64) {
        const int lane = tid;
        unsigned csum = 0;
        #pragma unroll
        for (int k = 0; k < CHUNK; ++k) csum += s_hist[lane * CHUNK + k];
        unsigned suff = csum;
        #pragma unroll
        for (int off = 1; off < 64; off <<= 1) {
            unsigned o = __shfl_down(suff, off);
            if (lane + off < 64) suff += o;
        }
        unsigned suff_next = __shfl_down(suff, 1);
        if (lane == 63) suff_next = 0;
        const bool hit = (suff >= rem_in) & (suff_next < rem_in);
        unsigned long long bmask = __ballot(hit);
        const int src = (int)__builtin_ctzll(bmask);
        const unsigned r_chunk = __shfl(rem_in - suff_next, src);
        const int      cbase   = src * CHUNK;
        unsigned h = (lane < CHUNK) ? s_hist[cbase + lane] : 0u;
        unsigned ssum = h;
        #pragma unroll
        for (int off = 1; off < CHUNK; off <<= 1) {
            unsigned o = __shfl_down(ssum, off);
            if (lane + off < CHUNK) ssum += o;
        }
        unsigned ssum_next = __shfl_down(ssum, 1);
        if (lane >= CHUNK - 1) ssum_next = 0;
        const bool hit2 = (lane < CHUNK) & (ssum >= r_chunk) & (ssum_next < r_chunk);
        if (hit2) {
            s_bcast[0] = (unsigned)(cbase + lane);
            s_bcast[1] = r_chunk - ssum_next;
        }
    }
}

// Same, over the SUM of two 4096-bin sub-histograms (wave-parity split).
__device__ inline void find_bin_4096x2(const unsigned* h0, const unsigned* h1,
                                       unsigned rem_in, unsigned* s_bcast, int tid)
{
    if (tid < 64) {
        const int lane = tid;
        unsigned csum = 0;
        #pragma unroll
        for (int k = 0; k < 64; ++k) {
            const int idx = lane * 64 + k;
            csum += h0[idx] + h1[idx];
        }
        unsigned suff = csum;
        #pragma unroll
        for (int off = 1; off < 64; off <<= 1) {
            unsigned o = __shfl_down(suff, off);
            if (lane + off < 64) suff += o;
        }
        unsigned suff_next = __shfl_down(suff, 1);
        if (lane == 63) suff_next = 0;
        const bool hit = (suff >= rem_in) & (suff_next < rem_in);
        unsigned long long bmask = __ballot(hit);
        const int src = (int)__builtin_ctzll(bmask);
        const unsigned r_chunk = __shfl(rem_in - suff_next, src);
        const int      cbase   = src * 64;
        unsigned hsum = h0[cbase + lane] + h1[cbase + lane];
        unsigned ssum = hsum;
        #pragma unroll
        for (int off = 1; off < 64; off <<= 1) {
            unsigned o = __shfl_down(ssum, off);
            if (lane + off < 64) ssum += o;
        }
        unsigned ssum_next = __shfl_down(ssum, 1);
        if (lane == 63) ssum_next = 0;
        const bool hit2 = (ssum >= r_chunk) & (ssum_next < r_chunk);
        if (hit2) {
            s_bcast[0] = (unsigned)(cbase + lane);
            s_bcast[1] = r_chunk - ssum_next;
        }
    }
}

__global__ __launch_bounds__(1024) void upsample_select_kernel(
    const float* __restrict__ att, unsigned long long* __restrict__ ws_bits)
{
    __shared__ float    s_in[NIN + 81];  // +81: zero pad so y1/x1 overruns are safe
    __shared__ unsigned s_hist[8192];    // 2 x 4096 sub-histograms (pass 1)
    __shared__ unsigned s_bcast[2];

    const int b   = blockIdx.x;
    const int tid = threadIdx.x;

    const float* in = att + b * NIN;
    for (int i = tid; i < NIN; i += 1024) s_in[i] = in[i];
    if (tid < 81) s_in[NIN + tid] = 0.0f;
    __syncthreads();

    // Branch-free bilinear 2x upsample, half-pixel centers. Edge clamping via
    // fmaxf (low edge) and wy/wx := 0 at the high edge; out-of-row/pad reads
    // are multiplied by exactly 0.0f -> results bit-identical to the
    // branchy version validated in rounds 1-9 (absmax==0).
    unsigned ub[25];
    #pragma unroll
    for (int j = 0; j < 25; ++j) {
        int i = j * 1024 + tid;
        int r = i / 160;
        int c = i - r * 160;
        float yf = fmaxf(0.5f * (float)r - 0.25f, 0.0f);
        int   y0 = (int)yf;
        float wy = yf - (float)y0;
        wy = (y0 >= 79) ? 0.0f : wy;
        float xf = fmaxf(0.5f * (float)c - 0.25f, 0.0f);
        int   x0 = (int)xf;
        float wx = xf - (float)x0;
        wx = (x0 >= 79) ? 0.0f : wx;
        const float* p0 = &s_in[y0 * 80 + x0];
        float a00 = p0[0], a01 = p0[1];        // merge -> ds_read2_b32
        float a10 = p0[80], a11 = p0[81];
        float top = a00 * (1.0f - wx) + a01 * wx;
        float bot = a10 * (1.0f - wx) + a11 * wx;
        float v   = top * (1.0f - wy) + bot * wy;
        ub[j] = __float_as_uint(v);   // v in [0,1) -> uint order == float order
    }

    // ---- exact radix select, 3 passes: bits [30:19], [18:9], [8:0] ----
    unsigned* myh = s_hist + ((tid >> 6) & 1) * 4096;
    for (int i = tid; i < 8192; i += 1024) s_hist[i] = 0;
    __syncthreads();
    #pragma unroll
    for (int j = 0; j < 25; ++j) atomicAdd(&myh[ub[j] >> 19], 1u);  // < 4096
    __syncthreads();
    find_bin_4096x2(s_hist, s_hist + 4096, KRANK, s_bcast, tid);
    __syncthreads();
    const unsigned p1  = s_bcast[0];
    unsigned       rem = s_bcast[1];
    __syncthreads();

    for (int i = tid; i < 1024; i += 1024) s_hist[i] = 0;
    __syncthreads();
    #pragma unroll
    for (int j = 0; j < 25; ++j) {
        unsigned u = ub[j];
        if ((u >> 19) == p1) atomicAdd(&s_hist[(u >> 9) & 1023u], 1u);
    }
    __syncthreads();
    find_bin<1024>(s_hist, rem, s_bcast, tid);
    __syncthreads();
    const unsigned pref2 = (p1 << 10) | s_bcast[0];    // bits [30:9]
    rem = s_bcast[1];
    __syncthreads();

    for (int i = tid; i < 512; i += 1024) s_hist[i] = 0;
    __syncthreads();
    #pragma unroll
    for (int j = 0; j < 25; ++j) {
        unsigned u = ub[j];
        if ((u >> 9) == pref2) atomicAdd(&s_hist[u & 511u], 1u);
    }
    __syncthreads();
    find_bin<512>(s_hist, rem, s_bcast, tid);
    __syncthreads();
    const unsigned thr_bits = (pref2 << 9) | s_bcast[0];

    // Output: ONLY the bit-packed mask (3.2 KB/batch). The fp32 mask plane is
    // derived from these bits by the apply kernel. Same values, same >=
    // comparison -> identical selected set.
    unsigned long long* wbptr = ws_bits + b * 400;   // 400 ull = 25600 bits
    const int lane = tid & 63;
    const int wv   = tid >> 6;
    #pragma unroll
    for (int j = 0; j < 25; ++j) {
        unsigned long long bal = __ballot(ub[j] >= thr_bits);  // bit i = elem j*1024+wv*64+i
        if (lane == 0) wbptr[j * 16 + wv] = bal;
    }
}

// weighted = local_feat * (mask + 0.1), plus mask fp32 materialization.
// One block per (b,c) plane; bit-packed mask in LDS (3.2 KB).
// ESTABLISHED: nt LOAD + PLAIN store (r6/r7/r8 A/B), full unroll for 25-deep
// MLP (r10, -10us), r10 ordering (s_bits stage first; r11 reorder was
// neutral). NEW: blocks with c<8 write 1/8 of their batch's fp32 mask plane
// from s_bits -- spreads the 800KB mask write across 64 CUs, hidden under
// the main stream, and removes it from the 8-CU select kernel.
__global__ __launch_bounds__(256) void apply_mask_kernel(
    const f32x4* __restrict__ feat, const unsigned* __restrict__ bits,
    f32x4* __restrict__ out, f32x4* __restrict__ mask_out)
{
    __shared__ unsigned s_bits[800];

    const int tid   = threadIdx.x;
    const int plane = blockIdx.x;          // b*256 + c
    const int b     = plane >> 8;
    const int c     = plane & 255;

    const unsigned* gb = bits + b * 800;
    #pragma unroll
    for (int k = 0; k < 3; ++k) s_bits[tid + k * 256] = gb[tid + k * 256];
    if (tid < 32) s_bits[768 + tid] = gb[768 + tid];
    __syncthreads();

    const f32x4* fp = feat + plane * 6400 + tid;
    f32x4*       op = out  + plane * 6400 + tid;

    f32x4 v[25];
    #pragma unroll
    for (int i = 0; i < 25; ++i)
        v[i] = __builtin_nontemporal_load(fp + i * 256);

    #pragma unroll
    for (int i = 0; i < 25; ++i) {
        const unsigned u   = (unsigned)(i * 256 + tid);        // f32x4 index in plane
        const unsigned nib = s_bits[u >> 3] >> ((u & 7u) * 4u);
        f32x4 w;
        w.x = (nib & 1u) ? 1.1f : 0.1f;   // 1.0f+0.1f == 1.1f bitwise (0x3F8CCCCD)
        w.y = (nib & 2u) ? 1.1f : 0.1f;
        w.z = (nib & 4u) ? 1.1f : 0.1f;
        w.w = (nib & 8u) ? 1.1f : 0.1f;
        op[i * 256] = v[i] * w;           // plain store
    }

    // epilogue: first 8 channel-blocks of each batch emit the fp32 mask plane
    // (800 f32x4 segment each) straight from the bits already in LDS.
    if (c < 8) {
        f32x4* mop = mask_out + b * 6400 + c * 800;
        #pragma unroll
        for (int t = 0; t < 4; ++t) {
            int k = t * 256 + tid;
            if (k < 800) {
                const unsigned nib = s_bits[(c * 800 + k) >> 3] >> (((c * 800 + k) & 7u) * 4u);
                f32x4 w;
                w.x = (nib & 1u) ? 1.0f : 0.0f;
                w.y = (nib & 2u) ? 1.0f : 0.0f;
                w.z = (nib & 4u) ? 1.0f : 0.0f;
                w.w = (nib & 8u) ? 1.0f : 0.0f;
                mop[k] = w;
            }
        }
    }
}

extern "C" void kernel_launch(void* const* d_in, const int* in_sizes, int n_in,
                              void* d_out, int out_size, void* d_ws, size_t ws_size,
                              hipStream_t stream)
{
    const float* local_feat = (const float*)d_in[0];   // (8,256,160,160) fp32
    const float* att        = (const float*)d_in[1];   // (8,1,80,80) fp32
    // d_in[2] = spatial_scale (==2, fixed by problem shapes)

    float* out      = (float*)d_out;
    float* mask_out = out + 8 * 256 * 160 * 160;       // second output region

    upsample_select_kernel<<<8, 1024, 0, stream>>>(
        att, (unsigned long long*)d_ws);

    apply_mask_kernel<<<2048, 256, 0, stream>>>(
        (const f32x4*)local_feat, (const unsigned*)d_ws,
        (f32x4*)out, (f32x4*)mask_out);
}

// Round 13
// 85.346 us; speedup vs baseline: 1.0231x; 1.0107x over previous
//
#include <hip/hip_runtime.h>

// RegionSelection: bilinear 2x upsample of attention map (8,1,80,80)->(8,1,160,160),
// per-batch rank-1921 threshold (k=int(0.3*6400)=1920, threshold=topv[:,k]),
// mask = up >= thr, weighted = local_feat*(mask+0.1).
// Outputs concatenated: weighted (8*256*160*160 fp32) then mask (8*160*160 fp32).
// d_ws: bit-packed mask, 400 ull per batch. Select writes ONLY the bitmask;
// the fp32 mask plane is materialized by the apply kernel (c<8 blocks).
//
// r13 experiment: (plain LOAD, nt STORE) -- the untested cache-policy cell.
// Mechanism under test: feat (200MB) fits Infinity Cache (256MB); plain loads
// may allocate it in L3 across graph-replay iterations while nt stores stream
// past L3, turning the read stream into L3 hits from iteration 2 onward.

#define NIN   6400    // 80*80
#define NUP   25600   // 160*160
#define KRANK 1921u   // (k+1)-th largest == topv[:, k]

typedef float f32x4 __attribute__((ext_vector_type(4)));

// Wave-parallel "find bin containing rank `rem_in` counting from the top" over
// NBINS bins. Two-level: 64 chunk sums + shfl suffix-scan, then a parallel
// scan of the selected chunk. Executed by wave 0; result -> s_bcast.
template <int NBINS>
__device__ inline void find_bin(const unsigned* s_hist, unsigned rem_in,
                                unsigned* s_bcast, int tid)
{
    constexpr int CHUNK = NBINS / 64;
    if (tid < 64) {
        const int lane = tid;
        unsigned csum = 0;
        #pragma unroll
        for (int k = 0; k < CHUNK; ++k) csum += s_hist[lane * CHUNK + k];
        unsigned suff = csum;
        #pragma unroll
        for (int off = 1; off < 64; off <<= 1) {
            unsigned o = __shfl_down(suff, off);
            if (lane + off < 64) suff += o;
        }
        unsigned suff_next = __shfl_down(suff, 1);
        if (lane == 63) suff_next = 0;
        const bool hit = (suff >= rem_in) & (suff_next < rem_in);
        unsigned long long bmask = __ballot(hit);
        const int src = (int)__builtin_ctzll(bmask);
        const unsigned r_chunk = __shfl(rem_in - suff_next, src);
        const int      cbase   = src * CHUNK;
        unsigned h = (lane < CHUNK) ? s_hist[cbase + lane] : 0u;
        unsigned ssum = h;
        #pragma unroll
        for (int off = 1; off < CHUNK; off <<= 1) {
            unsigned o = __shfl_down(ssum, off);
            if (lane + off < CHUNK) ssum += o;
        }
        unsigned ssum_next = __shfl_down(ssum, 1);
        if (lane >= CHUNK - 1) ssum_next = 0;
        const bool hit2 = (lane < CHUNK) & (ssum >= r_chunk) & (ssum_next < r_chunk);
        if (hit2) {
            s_bcast[0] = (unsigned)(cbase + lane);
            s_bcast[1] = r_chunk - ssum_next;
        }
    }
}

// Same, over the SUM of two 4096-bin sub-histograms (wave-parity split).
__device__ inline void find_bin_4096x2(const unsigned* h0, const unsigned* h1,
                                       unsigned rem_in, unsigned* s_bcast, int tid)
{
    if (tid < 64) {
        const int lane = tid;
        unsigned csum = 0;
        #pragma unroll
        for (int k = 0; k < 64; ++k) {
            const int idx = lane * 64 + k;
            csum += h0[idx] + h1[idx];
        }
        unsigned suff = csum;
        #pragma unroll
        for (int off = 1; off < 64; off <<= 1) {
            unsigned o = __shfl_down(suff, off);
            if (lane + off < 64) suff += o;
        }
        unsigned suff_next = __shfl_down(suff, 1);
        if (lane == 63) suff_next = 0;
        const bool hit = (suff >= rem_in) & (suff_next < rem_in);
        unsigned long long bmask = __ballot(hit);
        const int src = (int)__builtin_ctzll(bmask);
        const unsigned r_chunk = __shfl(rem_in - suff_next, src);
        const int      cbase   = src * 64;
        unsigned hsum = h0[cbase + lane] + h1[cbase + lane];
        unsigned ssum = hsum;
        #pragma unroll
        for (int off = 1; off < 64; off <<= 1) {
            unsigned o = __shfl_down(ssum, off);
            if (lane + off < 64) ssum += o;
        }
        unsigned ssum_next = __shfl_down(ssum, 1);
        if (lane == 63) ssum_next = 0;
        const bool hit2 = (ssum >= r_chunk) & (ssum_next < r_chunk);
        if (hit2) {
            s_bcast[0] = (unsigned)(cbase + lane);
            s_bcast[1] = r_chunk - ssum_next;
        }
    }
}

__global__ __launch_bounds__(1024) void upsample_select_kernel(
    const float* __restrict__ att, unsigned long long* __restrict__ ws_bits)
{
    __shared__ float    s_in[NIN + 81];  // +81: zero pad so y1/x1 overruns are safe
    __shared__ unsigned s_hist[8192];    // 2 x 4096 sub-histograms (pass 1)
    __shared__ unsigned s_bcast[2];

    const int b   = blockIdx.x;
    const int tid = threadIdx.x;

    const float* in = att + b * NIN;
    for (int i = tid; i < NIN; i += 1024) s_in[i] = in[i];
    if (tid < 81) s_in[NIN + tid] = 0.0f;
    __syncthreads();

    // Branch-free bilinear 2x upsample, half-pixel centers. Edge clamping via
    // fmaxf (low edge) and wy/wx := 0 at the high edge; out-of-row/pad reads
    // are multiplied by exactly 0.0f -> results bit-identical to the
    // branchy version validated in rounds 1-9 (absmax==0).
    unsigned ub[25];
    #pragma unroll
    for (int j = 0; j < 25; ++j) {
        int i = j * 1024 + tid;
        int r = i / 160;
        int c = i - r * 160;
        float yf = fmaxf(0.5f * (float)r - 0.25f, 0.0f);
        int   y0 = (int)yf;
        float wy = yf - (float)y0;
        wy = (y0 >= 79) ? 0.0f : wy;
        float xf = fmaxf(0.5f * (float)c - 0.25f, 0.0f);
        int   x0 = (int)xf;
        float wx = xf - (float)x0;
        wx = (x0 >= 79) ? 0.0f : wx;
        const float* p0 = &s_in[y0 * 80 + x0];
        float a00 = p0[0], a01 = p0[1];        // merge -> ds_read2_b32
        float a10 = p0[80], a11 = p0[81];
        float top = a00 * (1.0f - wx) + a01 * wx;
        float bot = a10 * (1.0f - wx) + a11 * wx;
        float v   = top * (1.0f - wy) + bot * wy;
        ub[j] = __float_as_uint(v);   // v in [0,1) -> uint order == float order
    }

    // ---- exact radix select, 3 passes: bits [30:19], [18:9], [8:0] ----
    unsigned* myh = s_hist + ((tid >> 6) & 1) * 4096;
    for (int i = tid; i < 8192; i += 1024) s_hist[i] = 0;
    __syncthreads();
    #pragma unroll
    for (int j = 0; j < 25; ++j) atomicAdd(&myh[ub[j] >> 19], 1u);  // < 4096
    __syncthreads();
    find_bin_4096x2(s_hist, s_hist + 4096, KRANK, s_bcast, tid);
    __syncthreads();
    const unsigned p1  = s_bcast[0];
    unsigned       rem = s_bcast[1];
    __syncthreads();

    for (int i = tid; i < 1024; i += 1024) s_hist[i] = 0;
    __syncthreads();
    #pragma unroll
    for (int j = 0; j < 25; ++j) {
        unsigned u = ub[j];
        if ((u >> 19) == p1) atomicAdd(&s_hist[(u >> 9) & 1023u], 1u);
    }
    __syncthreads();
    find_bin<1024>(s_hist, rem, s_bcast, tid);
    __syncthreads();
    const unsigned pref2 = (p1 << 10) | s_bcast[0];    // bits [30:9]
    rem = s_bcast[1];
    __syncthreads();

    for (int i = tid; i < 512; i += 1024) s_hist[i] = 0;
    __syncthreads();
    #pragma unroll
    for (int j = 0; j < 25; ++j) {
        unsigned u = ub[j];
        if ((u >> 9) == pref2) atomicAdd(&s_hist[u & 511u], 1u);
    }
    __syncthreads();
    find_bin<512>(s_hist, rem, s_bcast, tid);
    __syncthreads();
    const unsigned thr_bits = (pref2 << 9) | s_bcast[0];

    // Output: ONLY the bit-packed mask (3.2 KB/batch).
    unsigned long long* wbptr = ws_bits + b * 400;   // 400 ull = 25600 bits
    const int lane = tid & 63;
    const int wv   = tid >> 6;
    #pragma unroll
    for (int j = 0; j < 25; ++j) {
        unsigned long long bal = __ballot(ub[j] >= thr_bits);  // bit i = elem j*1024+wv*64+i
        if (lane == 0) wbptr[j * 16 + wv] = bal;
    }
}

// weighted = local_feat * (mask + 0.1), plus mask fp32 materialization.
// One block per (b,c) plane; bit-packed mask in LDS (3.2 KB); full unroll
// (25-deep MLP, r10). r13: PLAIN loads (may allocate feat in Infinity Cache
// across replay iterations) + NT stores (stream writes past the caches).
__global__ __launch_bounds__(256) void apply_mask_kernel(
    const f32x4* __restrict__ feat, const unsigned* __restrict__ bits,
    f32x4* __restrict__ out, f32x4* __restrict__ mask_out)
{
    __shared__ unsigned s_bits[800];

    const int tid   = threadIdx.x;
    const int plane = blockIdx.x;          // b*256 + c
    const int b     = plane >> 8;
    const int c     = plane & 255;

    const unsigned* gb = bits + b * 800;
    #pragma unroll
    for (int k = 0; k < 3; ++k) s_bits[tid + k * 256] = gb[tid + k * 256];
    if (tid < 32) s_bits[768 + tid] = gb[768 + tid];
    __syncthreads();

    const f32x4* fp = feat + plane * 6400 + tid;
    f32x4*       op = out  + plane * 6400 + tid;

    f32x4 v[25];
    #pragma unroll
    for (int i = 0; i < 25; ++i)
        v[i] = fp[i * 256];                        // PLAIN load (L2/L3 allocate)

    #pragma unroll
    for (int i = 0; i < 25; ++i) {
        const unsigned u   = (unsigned)(i * 256 + tid);        // f32x4 index in plane
        const unsigned nib = s_bits[u >> 3] >> ((u & 7u) * 4u);
        f32x4 w;
        w.x = (nib & 1u) ? 1.1f : 0.1f;   // 1.0f+0.1f == 1.1f bitwise (0x3F8CCCCD)
        w.y = (nib & 2u) ? 1.1f : 0.1f;
        w.z = (nib & 4u) ? 1.1f : 0.1f;
        w.w = (nib & 8u) ? 1.1f : 0.1f;
        __builtin_nontemporal_store(v[i] * w, op + i * 256);   // NT store
    }

    // epilogue: first 8 channel-blocks of each batch emit the fp32 mask plane
    // (800 f32x4 segment each) straight from the bits already in LDS.
    if (c < 8) {
        f32x4* mop = mask_out + b * 6400 + c * 800;
        #pragma unroll
        for (int t = 0; t < 4; ++t) {
            int k = t * 256 + tid;
            if (k < 800) {
                const unsigned nib = s_bits[(c * 800 + k) >> 3] >> (((c * 800 + k) & 7u) * 4u);
                f32x4 w;
                w.x = (nib & 1u) ? 1.0f : 0.0f;
                w.y = (nib & 2u) ? 1.0f : 0.0f;
                w.z = (nib & 4u) ? 1.0f : 0.0f;
                w.w = (nib & 8u) ? 1.0f : 0.0f;
                mop[k] = w;
            }
        }
    }
}

extern "C" void kernel_launch(void* const* d_in, const int* in_sizes, int n_in,
                              void* d_out, int out_size, void* d_ws, size_t ws_size,
                              hipStream_t stream)
{
    const float* local_feat = (const float*)d_in[0];   // (8,256,160,160) fp32
    const float* att        = (const float*)d_in[1];   // (8,1,80,80) fp32
    // d_in[2] = spatial_scale (==2, fixed by problem shapes)

    float* out      = (float*)d_out;
    float* mask_out = out + 8 * 256 * 160 * 160;       // second output region

    upsample_select_kernel<<<8, 1024, 0, stream>>>(
        att, (unsigned long long*)d_ws);

    apply_mask_kernel<<<2048, 256, 0, stream>>>(
        (const f32x4*)local_feat, (const unsigned*)d_ws,
        (f32x4*)out, (f32x4*)mask_out);
}